// Round 2
// baseline (673.424 us; speedup 1.0000x reference)
//
#include <hip/hip_runtime.h>
#include <hip/hip_bf16.h>

#define BB 4
#define SS 4096
#define EE 64
#define DD 512
#define QBLK 64
#define KVBLK 32
#define NIT (SS / KVBLK)

typedef __attribute__((ext_vector_type(4))) float f32x4;
typedef __attribute__((ext_vector_type(8))) _Float16 f16x8;
typedef unsigned short u16;

__device__ __forceinline__ u16 f2h(float f) {
  _Float16 h = (_Float16)f;
  return __builtin_bit_cast(u16, h);
}
__device__ __forceinline__ float h2f(u16 b) {
  return (float)__builtin_bit_cast(_Float16, b);
}

__device__ __forceinline__ void async16(const void* g, void* l) {
  __builtin_amdgcn_global_load_lds(
      (const __attribute__((address_space(1))) void*)g,
      (__attribute__((address_space(3))) void*)l, 16, 0, 0);
}

// ---------------- K1: qkv projection (fp32 VALU), emit fp16 ----------------
__global__ __launch_bounds__(256) void qkv_proj(
    const float* __restrict__ x,
    const float* __restrict__ Wq, const float* __restrict__ bq,
    const float* __restrict__ Wk, const float* __restrict__ bk,
    const float* __restrict__ Wv, const float* __restrict__ bv,
    u16* __restrict__ qb, u16* __restrict__ kb, u16* __restrict__ vb) {
  __shared__ float xs[32][EE];
  const int tid = threadIdx.x;
  const int row0 = blockIdx.x * 32;
  const float* W;
  const float* bias;
  u16* dst;
  if (blockIdx.y == 0) { W = Wq; bias = bq; dst = qb; }
  else if (blockIdx.y == 1) { W = Wk; bias = bk; dst = kb; }
  else { W = Wv; bias = bv; dst = vb; }

  // stage x tile (32 x 64 fp32)
  #pragma unroll
  for (int i = 0; i < 2; ++i) {
    int idx = tid + 256 * i;
    int r = idx >> 4, c = (idx & 15) * 4;
    *(float4*)&xs[r][c] = *(const float4*)&x[(size_t)(row0 + r) * EE + c];
  }
  __syncthreads();

  const int col = (tid & 127) * 4;
  const int rg = (tid >> 7) * 16;
  float acc[16][4];
  #pragma unroll
  for (int r = 0; r < 16; ++r)
    #pragma unroll
    for (int j = 0; j < 4; ++j) acc[r][j] = 0.f;

  for (int k = 0; k < EE; k += 4) {
    float4 wr[4];
    #pragma unroll
    for (int j = 0; j < 4; ++j) wr[j] = *(const float4*)&W[(size_t)(k + j) * DD + col];
    #pragma unroll
    for (int r = 0; r < 16; ++r) {
      float4 xv = *(const float4*)&xs[rg + r][k];
      acc[r][0] += xv.x * wr[0].x + xv.y * wr[1].x + xv.z * wr[2].x + xv.w * wr[3].x;
      acc[r][1] += xv.x * wr[0].y + xv.y * wr[1].y + xv.z * wr[2].y + xv.w * wr[3].y;
      acc[r][2] += xv.x * wr[0].z + xv.y * wr[1].z + xv.z * wr[2].z + xv.w * wr[3].z;
      acc[r][3] += xv.x * wr[0].w + xv.y * wr[1].w + xv.z * wr[2].w + xv.w * wr[3].w;
    }
  }

  const float4 b4 = *(const float4*)&bias[col];
  #pragma unroll
  for (int r = 0; r < 16; ++r) {
    ushort4 o;
    o.x = f2h(acc[r][0] + b4.x);
    o.y = f2h(acc[r][1] + b4.y);
    o.z = f2h(acc[r][2] + b4.z);
    o.w = f2h(acc[r][3] + b4.w);
    *(ushort4*)&dst[(size_t)(row0 + rg + r) * DD + col] = o;
  }
}

// ---------------- K2: flash attention, fp16 MFMA ----------------
// grid = 256 blocks (1/CU), 512 threads (8 waves).
// LDS: Qs 64KiB (swz) | Ks 32KiB (swz) | Vt 512x40 u16 (40KiB) | Ps 64x40 u16 (5KiB) | stats
__global__ __launch_bounds__(512, 2) void attn_fwd(
    const u16* __restrict__ qbuf, const u16* __restrict__ kbuf,
    const u16* __restrict__ vbuf, const float* __restrict__ mask,
    u16* __restrict__ zbuf) {
  extern __shared__ char smem[];
  u16* Qs = (u16*)smem;                                   // 64*512
  u16* Ks = (u16*)(smem + 65536);                         // 32*512
  u16* Vt = (u16*)(smem + 65536 + 32768);                 // 512*40
  u16* Ps = (u16*)(smem + 65536 + 32768 + 40960);         // 64*40
  float* m_row = (float*)(smem + 65536 + 32768 + 40960 + 5120);
  float* l_row = m_row + 64;
  float* alpha_row = l_row + 64;
  float* part_mx = alpha_row + 64;  // [2][64]
  float* part_sm = part_mx + 128;   // [2][64]

  const int tid = threadIdx.x;
  const int lane = tid & 63;
  const int w = tid >> 6;
  const int lrow = lane & 15, lhi = lane >> 4;

  // XCD-aware mapping: 32 blocks per XCD share one batch's K/V
  const int bid = blockIdx.x;
  const int xcd = bid & 7, slot = bid >> 3;
  const int b = xcd >> 1;
  const int q0 = ((xcd & 1) * 32 + slot) * QBLK;

  const int qw = w >> 1, tw = w & 1;   // QK: wave -> 16 q rows x 16 t cols
  const int qw2 = w >> 2, dw = w & 3;  // PV: wave -> 32 q rows x 128 d cols

  // ---- prologue: stage Q (64 rows), K tile 0, V tile 0 regs ----
  {
    const size_t gq = ((size_t)(b * SS + q0)) * DD;
    #pragma unroll
    for (int rr = 0; rr < 8; ++rr) {
      int row = w + rr * 8;
      const char* src = (const char*)(qbuf + gq + (size_t)row * DD);
      async16(src + ((lane * 16) ^ ((row & 7) << 4)), (char*)Qs + row * 1024);
    }
    const size_t gk = ((size_t)(b * SS + 0)) * DD;
    #pragma unroll
    for (int rr = 0; rr < 4; ++rr) {
      int row = w + rr * 8;
      const char* src = (const char*)(kbuf + gk + (size_t)row * DD);
      async16(src + ((lane * 16) ^ ((row & 7) << 4)), (char*)Ks + row * 1024);
    }
  }
  const int vt_t = tid & 31, vd0 = (tid >> 5) * 32;
  uint4 vreg[4];
  {
    const u16* vsrc = vbuf + ((size_t)(b * SS + vt_t)) * DD + vd0;
    #pragma unroll
    for (int i = 0; i < 4; ++i) vreg[i] = *(const uint4*)(vsrc + i * 8);
  }
  if (tid < 64) { m_row[tid] = -3.0e38f; l_row[tid] = 0.f; }

  f32x4 acc[2][8];
  #pragma unroll
  for (int fi = 0; fi < 2; ++fi)
    #pragma unroll
    for (int fj = 0; fj < 8; ++fj) acc[fi][fj] = (f32x4){0.f, 0.f, 0.f, 0.f};

  asm volatile("s_waitcnt vmcnt(0)" ::: "memory");
  __syncthreads();

  // precomputed per-lane bases
  const char* qrow_p = (const char*)Qs + (qw * 16 + lrow) * 1024;
  const char* krow_p = (const char*)Ks + (tw * 16 + lrow) * 1024;
  const int qswz = ((qw * 16 + lrow) & 7) << 4;
  const int kswz = ((tw * 16 + lrow) & 7) << 4;

  #pragma unroll 1
  for (int it = 0; it < NIT; ++it) {
    const int t0 = it * KVBLK;
    // 1) S = Q K^T over D=512 (16 k-steps)
    f32x4 s = (f32x4){0.f, 0.f, 0.f, 0.f};
    #pragma unroll
    for (int kk = 0; kk < 16; ++kk) {
      int off = kk * 64 + lhi * 16;
      f16x8 a = *(const f16x8*)(qrow_p + (off ^ qswz));
      f16x8 bf = *(const f16x8*)(krow_p + (off ^ kswz));
      s = __builtin_amdgcn_mfma_f32_16x16x32_f16(a, bf, s, 0, 0, 0);
    }
    // 2) + mask, 3) per-row partial max (over 16 lanes)
    {
      const size_t mbase =
          ((size_t)b * SS + (size_t)(q0 + qw * 16 + lhi * 4)) * SS + (size_t)(t0 + tw * 16 + lrow);
      #pragma unroll
      for (int r = 0; r < 4; ++r) s[r] += mask[mbase + (size_t)r * SS];
    }
    #pragma unroll
    for (int r = 0; r < 4; ++r) {
      float v = s[r];
      v = fmaxf(v, __shfl_xor(v, 1));
      v = fmaxf(v, __shfl_xor(v, 2));
      v = fmaxf(v, __shfl_xor(v, 4));
      v = fmaxf(v, __shfl_xor(v, 8));
      if (lrow == 0) part_mx[tw * 64 + qw * 16 + lhi * 4 + r] = v;
    }
    __syncthreads();  // (4) partial maxes visible; prev PV done -> Vt/Ps writable

    // 5) write V^T into LDS; wave0 lanes compute new max + alpha
    #pragma unroll
    for (int i = 0; i < 4; ++i) {
      union { uint4 u; u16 h[8]; } cv;
      cv.u = vreg[i];
      #pragma unroll
      for (int e = 0; e < 8; ++e) Vt[(vd0 + i * 8 + e) * 40 + vt_t] = cv.h[e];
    }
    if (tid < 64) {
      float mo = m_row[tid];
      float mt = fmaxf(part_mx[tid], part_mx[64 + tid]);
      float mn = fmaxf(mo, mt);
      m_row[tid] = mn;
      alpha_row[tid] = __expf(mo - mn);
    }
    __syncthreads();  // (6) m/alpha + Vt ready

    // 7) P = exp(S - m), write Ps (fp16), partial sums; rescale O by alpha
    #pragma unroll
    for (int r = 0; r < 4; ++r) {
      float mn = m_row[qw * 16 + lhi * 4 + r];
      float p = __expf(s[r] - mn);
      Ps[(qw * 16 + lhi * 4 + r) * 40 + tw * 16 + lrow] = f2h(p);
      float v = p;
      v += __shfl_xor(v, 1);
      v += __shfl_xor(v, 2);
      v += __shfl_xor(v, 4);
      v += __shfl_xor(v, 8);
      if (lrow == 0) part_sm[tw * 64 + qw * 16 + lhi * 4 + r] = v;
    }
    #pragma unroll
    for (int fi = 0; fi < 2; ++fi) {
      #pragma unroll
      for (int r = 0; r < 4; ++r) {
        float al = alpha_row[qw2 * 32 + fi * 16 + lhi * 4 + r];
        #pragma unroll
        for (int fj = 0; fj < 8; ++fj) acc[fi][fj][r] *= al;
      }
    }
    __syncthreads();  // (8) Ps + partial sums ready

    if (tid < 64)
      l_row[tid] = alpha_row[tid] * l_row[tid] + part_sm[tid] + part_sm[64 + tid];

    // 9) O += P @ V  (K=32, one MFMA per fragment pair)
    {
      f16x8 afr[2];
      #pragma unroll
      for (int fi = 0; fi < 2; ++fi)
        afr[fi] = *(const f16x8*)(Ps + (qw2 * 32 + fi * 16 + lrow) * 40 + lhi * 8);
      #pragma unroll
      for (int fj = 0; fj < 8; ++fj) {
        f16x8 bf = *(const f16x8*)(Vt + (dw * 128 + fj * 16 + lrow) * 40 + lhi * 8);
        #pragma unroll
        for (int fi = 0; fi < 2; ++fi)
          acc[fi][fj] = __builtin_amdgcn_mfma_f32_16x16x32_f16(afr[fi], bf, acc[fi][fj], 0, 0, 0);
      }
    }

    // 10) stage next K tile + next V regs
    if (it + 1 < NIT) {
      const int tn = t0 + KVBLK;
      const size_t gk = ((size_t)(b * SS + tn)) * DD;
      #pragma unroll
      for (int rr = 0; rr < 4; ++rr) {
        int row = w + rr * 8;
        const char* src = (const char*)(kbuf + gk + (size_t)row * DD);
        async16(src + ((lane * 16) ^ ((row & 7) << 4)), (char*)Ks + row * 1024);
      }
      const u16* vsrc = vbuf + ((size_t)(b * SS + tn + vt_t)) * DD + vd0;
      #pragma unroll
      for (int i = 0; i < 4; ++i) vreg[i] = *(const uint4*)(vsrc + i * 8);
    }
    asm volatile("s_waitcnt vmcnt(0)" ::: "memory");
    __syncthreads();  // (12) next K ready; Ps/Vt consumers done
  }

  // epilogue: z = O / l / 64^0.25 -> fp16
  const float inv_s = 0.35355339059327373f;
  #pragma unroll
  for (int fi = 0; fi < 2; ++fi) {
    #pragma unroll
    for (int r = 0; r < 4; ++r) {
      int qrow = qw2 * 32 + fi * 16 + lhi * 4 + r;
      float rl = inv_s / l_row[qrow];
      size_t base = ((size_t)(b * SS + q0 + qrow)) * DD + (size_t)(dw * 128 + lrow);
      #pragma unroll
      for (int fj = 0; fj < 8; ++fj) zbuf[base + fj * 16] = f2h(acc[fi][fj][r] * rl);
    }
  }
}

// ---------------- K3: out = z @ Wo + bo (fp32 VALU) ----------------
__global__ __launch_bounds__(256) void out_proj(
    const u16* __restrict__ zbuf, const float* __restrict__ Wo,
    const float* __restrict__ bo, float* __restrict__ out) {
  __shared__ float zs[32][DD];
  const int tid = threadIdx.x;
  const int row0 = blockIdx.x * 32;
  #pragma unroll
  for (int i = 0; i < 8; ++i) {
    int idx = tid + 256 * i;
    int r = idx >> 6, off = (idx & 63) * 8;
    uint4 u = *(const uint4*)(zbuf + (size_t)(row0 + r) * DD + off);
    union { uint4 uu; u16 h[8]; } cv;
    cv.uu = u;
    #pragma unroll
    for (int e = 0; e < 8; ++e) zs[r][off + e] = h2f(cv.h[e]);
  }
  __syncthreads();

  const int col = tid & 63;
  const int rg = (tid >> 6) * 8;
  float acc[8];
  #pragma unroll
  for (int r = 0; r < 8; ++r) acc[r] = 0.f;

  for (int k = 0; k < DD; k += 4) {
    float w0 = Wo[(size_t)k * EE + col];
    float w1 = Wo[(size_t)(k + 1) * EE + col];
    float w2 = Wo[(size_t)(k + 2) * EE + col];
    float w3 = Wo[(size_t)(k + 3) * EE + col];
    #pragma unroll
    for (int r = 0; r < 8; ++r) {
      float4 z4 = *(const float4*)&zs[rg + r][k];
      acc[r] += z4.x * w0 + z4.y * w1 + z4.z * w2 + z4.w * w3;
    }
  }
  float bv = bo[col];
  #pragma unroll
  for (int r = 0; r < 8; ++r)
    out[(size_t)(row0 + rg + r) * EE + col] = acc[r] + bv;
}

extern "C" void kernel_launch(void* const* d_in, const int* in_sizes, int n_in,
                              void* d_out, int out_size, void* d_ws, size_t ws_size,
                              hipStream_t stream) {
  const float* x = (const float*)d_in[0];
  const float* mask = (const float*)d_in[1];
  const float* Wq = (const float*)d_in[2];
  const float* bq = (const float*)d_in[3];
  const float* Wk = (const float*)d_in[4];
  const float* bk = (const float*)d_in[5];
  const float* Wv = (const float*)d_in[6];
  const float* bv = (const float*)d_in[7];
  const float* Wo = (const float*)d_in[8];
  const float* bo = (const float*)d_in[9];
  float* out = (float*)d_out;

  u16* qb = (u16*)d_ws;
  u16* kb = qb + (size_t)BB * SS * DD;
  u16* vb = kb + (size_t)BB * SS * DD;
  u16* zb = vb + (size_t)BB * SS * DD;

  qkv_proj<<<dim3(BB * SS / 32, 3), 256, 0, stream>>>(x, Wq, bq, Wk, bk, Wv, bv, qb, kb, vb);

  size_t smem = 65536 + 32768 + 40960 + 5120 + (size_t)(64 * 3 + 128 * 2) * 4;
  attn_fwd<<<256, 512, smem, stream>>>(qb, kb, vb, mask, zb);

  out_proj<<<BB * SS / 32, 256, 0, stream>>>(zb, Wo, bo, out);
}

// Round 4
// 567.771 us; speedup vs baseline: 1.1861x; 1.1861x over previous
//
#include <hip/hip_runtime.h>
#include <hip/hip_bf16.h>

#define BB 4
#define SS 4096
#define EE 64
#define DD 512
#define QBLK 64
#define KVBLK 32
#define NIT (SS / KVBLK)

typedef __attribute__((ext_vector_type(4))) float f32x4;
typedef __attribute__((ext_vector_type(8))) _Float16 f16x8;
typedef unsigned short u16;
typedef unsigned int u32;

__device__ __forceinline__ u16 f2h(float f) {
  _Float16 h = (_Float16)f;
  return __builtin_bit_cast(u16, h);
}
__device__ __forceinline__ float h2f(u16 b) {
  return (float)__builtin_bit_cast(_Float16, b);
}

__device__ __forceinline__ void async16(const void* g, void* l) {
  __builtin_amdgcn_global_load_lds(
      (const __attribute__((address_space(1))) void*)g,
      (__attribute__((address_space(3))) void*)l, 16, 0, 0);
}

// ---------------- K1: qkv projection (fp32 VALU), emit fp16 ----------------
__global__ __launch_bounds__(256) void qkv_proj(
    const float* __restrict__ x,
    const float* __restrict__ Wq, const float* __restrict__ bq,
    const float* __restrict__ Wk, const float* __restrict__ bk,
    const float* __restrict__ Wv, const float* __restrict__ bv,
    u16* __restrict__ qb, u16* __restrict__ kb, u16* __restrict__ vb) {
  __shared__ float xs[32][EE];
  const int tid = threadIdx.x;
  const int row0 = blockIdx.x * 32;
  const float* W;
  const float* bias;
  u16* dst;
  if (blockIdx.y == 0) { W = Wq; bias = bq; dst = qb; }
  else if (blockIdx.y == 1) { W = Wk; bias = bk; dst = kb; }
  else { W = Wv; bias = bv; dst = vb; }

  #pragma unroll
  for (int i = 0; i < 2; ++i) {
    int idx = tid + 256 * i;
    int r = idx >> 4, c = (idx & 15) * 4;
    *(float4*)&xs[r][c] = *(const float4*)&x[(size_t)(row0 + r) * EE + c];
  }
  __syncthreads();

  const int col = (tid & 127) * 4;
  const int rg = (tid >> 7) * 16;
  float acc[16][4];
  #pragma unroll
  for (int r = 0; r < 16; ++r)
    #pragma unroll
    for (int j = 0; j < 4; ++j) acc[r][j] = 0.f;

  for (int k = 0; k < EE; k += 4) {
    float4 wr[4];
    #pragma unroll
    for (int j = 0; j < 4; ++j) wr[j] = *(const float4*)&W[(size_t)(k + j) * DD + col];
    #pragma unroll
    for (int r = 0; r < 16; ++r) {
      float4 xv = *(const float4*)&xs[rg + r][k];
      acc[r][0] += xv.x * wr[0].x + xv.y * wr[1].x + xv.z * wr[2].x + xv.w * wr[3].x;
      acc[r][1] += xv.x * wr[0].y + xv.y * wr[1].y + xv.z * wr[2].y + xv.w * wr[3].y;
      acc[r][2] += xv.x * wr[0].z + xv.y * wr[1].z + xv.z * wr[2].z + xv.w * wr[3].z;
      acc[r][3] += xv.x * wr[0].w + xv.y * wr[1].w + xv.z * wr[2].w + xv.w * wr[3].w;
    }
  }

  const float4 b4 = *(const float4*)&bias[col];
  #pragma unroll
  for (int r = 0; r < 16; ++r) {
    ushort4 o;
    o.x = f2h(acc[r][0] + b4.x);
    o.y = f2h(acc[r][1] + b4.y);
    o.z = f2h(acc[r][2] + b4.z);
    o.w = f2h(acc[r][3] + b4.w);
    *(ushort4*)&dst[(size_t)(row0 + rg + r) * DD + col] = o;
  }
}

// ---------------- K2: flash attention v3 ----------------
// 256 blocks (1/CU), 512 threads (8 waves).
// Q in regs; swapped QK^T (S^T in regs); K dbuf via global_load_lds (swizzled);
// V dbuf transposed via reg-pack + ds_write_b128; defer-max.
// LDS: Ks[2][32][512] 64K | Vt[2][512][40] 80K | Ps[64][40] 5K | stats ~1.5K
__global__ __launch_bounds__(512) void attn_fwd(
    const u16* __restrict__ qbuf, const u16* __restrict__ kbuf,
    const u16* __restrict__ vbuf, const float* __restrict__ mask,
    u16* __restrict__ zbuf) {
  extern __shared__ char smem[];
  u16* Ks = (u16*)smem;                       // 2 x 32768 B
  u16* Vt = (u16*)(smem + 65536);             // 2 x 40960 B
  u16* Ps = (u16*)(smem + 147456);            // 64 x 40 u16
  float* pmx = (float*)(smem + 152576);       // [2][64]
  float* psm = (float*)(smem + 153088);       // [2][64]
  float* alr = (float*)(smem + 153600);       // [64]
  float* lro = (float*)(smem + 153856);       // [64]

  const int tid = threadIdx.x;
  const int lane = tid & 63;
  const int w = tid >> 6;
  const int lrow = lane & 15, lhi = lane >> 4;

  const int bid = blockIdx.x;
  const int xcd = bid & 7, slot = bid >> 3;
  const int b = xcd >> 1;
  const int q0 = ((xcd & 1) * 32 + slot) * QBLK;

  const int qw = w >> 1, tw = w & 1;   // QK: 16 q-rows x 16 t-cols per wave
  const int qw2 = w >> 2, dw = w & 3;  // PV: 32 q-rows x 128 d-cols per wave
  const int row16 = qw * 16 + lrow;    // this lane's q-row (local)
  const int qrow = q0 + row16;         // global q-row

  // ---- Q -> registers (B-operand frags: lane needs Q[qrow][kk*32 + lhi*8 + j]) ----
  f16x8 qreg[16];
  {
    const u16* qg = qbuf + ((size_t)b * SS + qrow) * DD + lhi * 8;
    #pragma unroll
    for (int kk = 0; kk < 16; ++kk) qreg[kk] = *(const f16x8*)(qg + kk * 32);
  }

  // ---- stage K tile 0 (async, swizzled) ----
  {
    const char* kg = (const char*)(kbuf + ((size_t)b * SS) * DD);
    #pragma unroll
    for (int rr = 0; rr < 4; ++rr) {
      int row = w + rr * 8;
      async16(kg + (size_t)row * 1024 + ((lane * 16) ^ ((row & 7) << 4)),
              (char*)Ks + row * 1024);
    }
  }
  // ---- V tile 0 -> regs (8t x 4d block per thread) ----
  const int vt0l = (tid & 3) * 8;
  const int vd0 = (tid >> 2) * 4;
  uint2 vreg[8];
  {
    const u16* vg = vbuf + ((size_t)b * SS + vt0l) * DD + vd0;
    #pragma unroll
    for (int i = 0; i < 8; ++i) vreg[i] = *(const uint2*)(vg + (size_t)i * DD);
  }

  auto write_vt = [&](u16* dst) {
    #pragma unroll
    for (int e = 0; e < 4; ++e) {
      u32 h[8];
      #pragma unroll
      for (int i = 0; i < 8; ++i) {
        u32 word = (e < 2) ? vreg[i].x : vreg[i].y;
        h[i] = (word >> ((e & 1) * 16)) & 0xFFFFu;
      }
      uint4 wv;
      wv.x = h[0] | (h[1] << 16);
      wv.y = h[2] | (h[3] << 16);
      wv.z = h[4] | (h[5] << 16);
      wv.w = h[6] | (h[7] << 16);
      *(uint4*)&dst[(vd0 + e) * 40 + vt0l] = wv;
    }
  };

  float m_reg = -3.0e38f, l_reg = 0.f;
  f32x4 acc[2][8];
  #pragma unroll
  for (int fi = 0; fi < 2; ++fi)
    #pragma unroll
    for (int fj = 0; fj < 8; ++fj) acc[fi][fj] = (f32x4){0.f, 0.f, 0.f, 0.f};

  asm volatile("s_waitcnt vmcnt(0)" ::: "memory");
  write_vt(Vt);  // Vt buffer 0
  __syncthreads();

  const int krow_off = (tw * 16 + lrow) * 1024;
  const int kswz = (lrow & 7) << 4;

  #pragma unroll 1
  for (int it = 0; it < NIT; ++it) {
    const int cur = it & 1;
    const int t0 = it * KVBLK;
    u16* vt_cur = Vt + cur * (512 * 40);

    // --- phase A: mask load FIRST (so its wait leaves prefetch in flight) ---
    const size_t mbase = ((size_t)b * SS + qrow) * SS + (size_t)(t0 + tw * 16 + lhi * 4);
    const float4 mv = *(const float4*)&mask[mbase];

    if (it + 1 < NIT) {
      const char* kg = (const char*)(kbuf + ((size_t)(b * SS + t0 + KVBLK)) * DD);
      char* kd = (char*)Ks + ((it + 1) & 1) * 32768;
      #pragma unroll
      for (int rr = 0; rr < 4; ++rr) {
        int row = w + rr * 8;
        async16(kg + (size_t)row * 1024 + ((lane * 16) ^ ((row & 7) << 4)),
                kd + row * 1024);
      }
      const u16* vg = vbuf + ((size_t)(b * SS + t0 + KVBLK) + vt0l) * DD + vd0;
      #pragma unroll
      for (int i = 0; i < 8; ++i) vreg[i] = *(const uint2*)(vg + (size_t)i * DD);
    }

    // --- QK^T swapped: s holds S^T -> lane = 4 t-values of q-row `qrow` ---
    f32x4 s = (f32x4){0.f, 0.f, 0.f, 0.f};
    {
      const char* kp = (const char*)Ks + cur * 32768 + krow_off;
      #pragma unroll
      for (int kk = 0; kk < 16; ++kk) {
        int off = kk * 64 + lhi * 16;
        f16x8 kf = *(const f16x8*)(kp + (off ^ kswz));
        s = __builtin_amdgcn_mfma_f32_16x16x32_f16(kf, qreg[kk], s, 0, 0, 0);
      }
    }
    s[0] += mv.x; s[1] += mv.y; s[2] += mv.z; s[3] += mv.w;

    // --- row max over this wave's 16 t (local 4 + lhi groups) ---
    float pmax = fmaxf(fmaxf(s[0], s[1]), fmaxf(s[2], s[3]));
    pmax = fmaxf(pmax, __shfl_xor(pmax, 16));
    pmax = fmaxf(pmax, __shfl_xor(pmax, 32));
    if (lhi == 0) pmx[tw * 64 + row16] = pmax;
    __syncthreads();  // B1

    const float mt = fmaxf(pmx[row16], pmx[64 + row16]);
    float al;
    if (__any(mt - m_reg > 8.0f)) {  // defer-max: wave-uniform, tw-consistent
      float mn = fmaxf(m_reg, mt);
      al = __expf(m_reg - mn);
      m_reg = mn;
    } else {
      al = 1.0f;
    }
    const float p0 = __expf(s[0] - m_reg);
    const float p1 = __expf(s[1] - m_reg);
    const float p2 = __expf(s[2] - m_reg);
    const float p3 = __expf(s[3] - m_reg);
    float psum = (p0 + p1) + (p2 + p3);
    psum += __shfl_xor(psum, 16);
    psum += __shfl_xor(psum, 32);
    {
      uint2 pw;
      pw.x = (u32)f2h(p0) | ((u32)f2h(p1) << 16);
      pw.y = (u32)f2h(p2) | ((u32)f2h(p3) << 16);
      *(uint2*)&Ps[row16 * 40 + tw * 16 + lhi * 4] = pw;
    }
    if (lhi == 0) {
      psm[tw * 64 + row16] = psum;
      if (tw == 0) alr[row16] = al;
    }
    __syncthreads();  // B2

    l_reg = al * l_reg + (psm[row16] + psm[64 + row16]);

    // --- rescale acc by alpha (skip when uniformly deferred) ---
    {
      float af[2][4];
      #pragma unroll
      for (int fi = 0; fi < 2; ++fi)
        #pragma unroll
        for (int r = 0; r < 4; ++r)
          af[fi][r] = alr[qw2 * 32 + fi * 16 + lhi * 4 + r];
      int ones = (af[0][0] == 1.f) & (af[0][1] == 1.f) & (af[0][2] == 1.f) &
                 (af[0][3] == 1.f) & (af[1][0] == 1.f) & (af[1][1] == 1.f) &
                 (af[1][2] == 1.f) & (af[1][3] == 1.f);
      if (!__all(ones)) {
        #pragma unroll
        for (int fi = 0; fi < 2; ++fi)
          #pragma unroll
          for (int r = 0; r < 4; ++r)
            #pragma unroll
            for (int fj = 0; fj < 8; ++fj) acc[fi][fj][r] *= af[fi][r];
      }
    }

    // --- PV: O += P @ V ---
    {
      f16x8 afr[2];
      afr[0] = *(const f16x8*)&Ps[(qw2 * 32 + lrow) * 40 + lhi * 8];
      afr[1] = *(const f16x8*)&Ps[(qw2 * 32 + 16 + lrow) * 40 + lhi * 8];
      #pragma unroll
      for (int fj = 0; fj < 8; ++fj) {
        f16x8 bf = *(const f16x8*)&vt_cur[(dw * 128 + fj * 16 + lrow) * 40 + lhi * 8];
        acc[0][fj] = __builtin_amdgcn_mfma_f32_16x16x32_f16(afr[0], bf, acc[0][fj], 0, 0, 0);
        acc[1][fj] = __builtin_amdgcn_mfma_f32_16x16x32_f16(afr[1], bf, acc[1][fj], 0, 0, 0);
      }
    }

    // --- drain prefetch, write next V^T ---
    asm volatile("s_waitcnt vmcnt(0)" ::: "memory");
    if (it + 1 < NIT) write_vt(Vt + ((it + 1) & 1) * (512 * 40));
    __syncthreads();  // B3
  }

  // ---- epilogue ----
  if (tw == 0 && lhi == 0) lro[row16] = l_reg;
  __syncthreads();
  const float inv_s = 0.35355339059327373f;
  #pragma unroll
  for (int fi = 0; fi < 2; ++fi) {
    #pragma unroll
    for (int r = 0; r < 4; ++r) {
      int row = qw2 * 32 + fi * 16 + lhi * 4 + r;
      float rl = inv_s / lro[row];
      size_t base = ((size_t)b * SS + (size_t)(q0 + row)) * DD + (size_t)(dw * 128 + lrow);
      #pragma unroll
      for (int fj = 0; fj < 8; ++fj) zbuf[base + fj * 16] = f2h(acc[fi][fj][r] * rl);
    }
  }
}

// ---------------- K3: out = z @ Wo + bo (fp32 VALU) ----------------
__global__ __launch_bounds__(256) void out_proj(
    const u16* __restrict__ zbuf, const float* __restrict__ Wo,
    const float* __restrict__ bo, float* __restrict__ out) {
  __shared__ float zs[32][DD];
  const int tid = threadIdx.x;
  const int row0 = blockIdx.x * 32;
  #pragma unroll
  for (int i = 0; i < 8; ++i) {
    int idx = tid + 256 * i;
    int r = idx >> 6, off = (idx & 63) * 8;
    uint4 u = *(const uint4*)(zbuf + (size_t)(row0 + r) * DD + off);
    union { uint4 uu; u16 h[8]; } cv;
    cv.uu = u;
    #pragma unroll
    for (int e = 0; e < 8; ++e) zs[r][off + e] = h2f(cv.h[e]);
  }
  __syncthreads();

  const int col = tid & 63;
  const int rg = (tid >> 6) * 8;
  float acc[8];
  #pragma unroll
  for (int r = 0; r < 8; ++r) acc[r] = 0.f;

  for (int k = 0; k < DD; k += 4) {
    float w0 = Wo[(size_t)k * EE + col];
    float w1 = Wo[(size_t)(k + 1) * EE + col];
    float w2 = Wo[(size_t)(k + 2) * EE + col];
    float w3 = Wo[(size_t)(k + 3) * EE + col];
    #pragma unroll
    for (int r = 0; r < 8; ++r) {
      float4 z4 = *(const float4*)&zs[rg + r][k];
      acc[r] += z4.x * w0 + z4.y * w1 + z4.z * w2 + z4.w * w3;
    }
  }
  float bv = bo[col];
  #pragma unroll
  for (int r = 0; r < 8; ++r)
    out[(size_t)(row0 + rg + r) * EE + col] = acc[r] + bv;
}

extern "C" void kernel_launch(void* const* d_in, const int* in_sizes, int n_in,
                              void* d_out, int out_size, void* d_ws, size_t ws_size,
                              hipStream_t stream) {
  const float* x = (const float*)d_in[0];
  const float* mask = (const float*)d_in[1];
  const float* Wq = (const float*)d_in[2];
  const float* bq = (const float*)d_in[3];
  const float* Wk = (const float*)d_in[4];
  const float* bk = (const float*)d_in[5];
  const float* Wv = (const float*)d_in[6];
  const float* bv = (const float*)d_in[7];
  const float* Wo = (const float*)d_in[8];
  const float* bo = (const float*)d_in[9];
  float* out = (float*)d_out;

  u16* qb = (u16*)d_ws;
  u16* kb = qb + (size_t)BB * SS * DD;
  u16* vb = kb + (size_t)BB * SS * DD;
  u16* zb = vb + (size_t)BB * SS * DD;

  qkv_proj<<<dim3(BB * SS / 32, 3), 256, 0, stream>>>(x, Wq, bq, Wk, bk, Wv, bv, qb, kb, vb);

  attn_fwd<<<256, 512, 154112, stream>>>(qb, kb, vb, mask, zb);

  out_proj<<<BB * SS / 32, 256, 0, stream>>>(zb, Wo, bo, out);
}